// Round 1
// 236.615 us; speedup vs baseline: 1.0064x; 1.0064x over previous
//
#include <hip/hip_runtime.h>
#include <math.h>

// SpectralConv1d: y = irfft( einsum('bim,iom->bom', rfft(x)[:,:,:16], W) )
// B=64, Cin=64, Cout=64, MODES=16, RES=8192.
// v2: 512-thread blocks, one sample-column per thread; interleaved-complex LDS;
// shuffle reductions; C in SGPRs; launch_bounds(512,8) -> 32 waves/CU.

#define B_     64
#define CIN_   64
#define COUT_  64
#define MODES_ 16
#define RES_   8192
#define NA     512          // RES_/16
#define TPITCH 515          // float2 pitch for Ts rows; 515 % 16 == 3 (bank spread)
#define W8192  7.66990393942820428e-4f   // 2*pi/8192

__device__ static constexpr float COS16[16] = {
     1.0f,  0.92387953251128674f,  0.70710678118654752f,  0.38268343236508977f,
     0.0f, -0.38268343236508977f, -0.70710678118654752f, -0.92387953251128674f,
    -1.0f, -0.92387953251128674f, -0.70710678118654752f, -0.38268343236508977f,
     0.0f,  0.38268343236508977f,  0.70710678118654752f,  0.92387953251128674f
};
__device__ static constexpr float SIN16[16] = {
     0.0f,  0.38268343236508977f,  0.70710678118654752f,  0.92387953251128674f,
     1.0f,  0.92387953251128674f,  0.70710678118654752f,  0.38268343236508977f,
     0.0f, -0.38268343236508977f, -0.70710678118654752f, -0.92387953251128674f,
    -1.0f, -0.92387953251128674f, -0.70710678118654752f, -0.38268343236508977f
};

// ---------------- Stage A: X[row,k] = sum_n x[row,n] e^{-2pi i k n/8192}, k=0..15
// One block per row (4096 blocks), 512 threads, one a-column per thread.
__global__ __launch_bounds__(512, 8) void kA(const float* __restrict__ x,
                                             float* __restrict__ X) {
    __shared__ float2 Ts[9 * TPITCH];      // t_k[a] interleaved (re,im), k=0..8: 37080 B
    __shared__ float  Pred[8][16][2];      // per-wave partials: 1024 B
    const int row = blockIdx.x;
    const int tid = threadIdx.x;
    const float* __restrict__ xr = x + (size_t)row * RES_;

    // Phase 1: 16-pt real DFT over b at a = tid (even/odd folded).
    float m[16];
#pragma unroll
    for (int b = 0; b < 16; ++b) m[b] = xr[tid + NA * b];
    float ev[8], ov[8];
#pragma unroll
    for (int b = 1; b <= 7; ++b) { ev[b] = m[b] + m[16 - b]; ov[b] = m[b] - m[16 - b]; }
    const float x0 = m[0], x8 = m[8];
#pragma unroll
    for (int k = 0; k <= 8; ++k) {
        float sr = (k & 1) ? (x0 - x8) : (x0 + x8);
        float si = 0.f;
#pragma unroll
        for (int b = 1; b <= 7; ++b) {
            sr = fmaf(ev[b],  COS16[(k * b) & 15], sr);
            si = fmaf(ov[b], -SIN16[(k * b) & 15], si);
        }
        Ts[k * TPITCH + tid] = make_float2(sr, si);
    }
    __syncthreads();

    // Phase 2: X[k] = sum_a e^{-2pi i k a/8192} t_k[a]; a = c + 32*j.
    // Hermitian t: k>8 -> conj t[16-k]; sign folded into the twiddle (primed vars).
    const int k  = tid & 15;
    const int c  = tid >> 4;               // 0..31
    const int kp = (k <= 8) ? k : 16 - k;
    const float sgn = (k <= 8) ? 1.f : -1.f;
    float sA, cA, sB, cB;
    __sincosf((float)(k * c)  * W8192, &sA, &cA);
    __sincosf((float)(k * 32) * W8192, &sB, &cB);
    float wre = cA, wim = -sgn * sA;       // primed: wim' = sgn*wim_true
    const float sre = cB, sim = -sgn * sB; // primed step
    float accr = 0.f, acci = 0.f;          // acci holds sgn*Im
    const float2* __restrict__ Tp = &Ts[kp * TPITCH + c];
#pragma unroll
    for (int j = 0; j < 16; ++j) {
        const float2 t = Tp[32 * j];
        accr = fmaf(wre, t.x, fmaf(-wim, t.y, accr));
        acci = fmaf(wre, t.y, fmaf( wim, t.x, acci));
        const float nre = fmaf(wre, sre, -wim * sim);
        wim = fmaf(wre, sim, wim * sre);
        wre = nre;
    }
    acci *= sgn;
    // reduce the 4 c-values that share k within this wave (lanes k, k+16, k+32, k+48)
    accr += __shfl_xor(accr, 16, 64);  acci += __shfl_xor(acci, 16, 64);
    accr += __shfl_xor(accr, 32, 64);  acci += __shfl_xor(acci, 32, 64);
    if ((tid & 63) < 16) {
        *(float2*)&Pred[tid >> 6][k][0] = make_float2(accr, acci);
    }
    __syncthreads();
    if (tid < 32) {                        // tid = 2k+comp
        const int kk = tid >> 1, comp = tid & 1;
        float s = 0.f;
#pragma unroll
        for (int w = 0; w < 8; ++w) s += Pred[w][kk][comp];
        X[row * 32 + tid] = s;
    }
}

// ---------------- Stage C (fused B+C): per block (b,o):
//   C_k = g_k * sum_i X[b,i,k] * W[i,o,k]   (g_0=1/N, g_k=2/N)
//   y[a+512*bb] = sum_k Re( C_k e^{2pi i k a/8192} e^{i pi k bb/8} )
// One block per output row (4096 blocks), 512 threads, one a per thread.
__global__ __launch_bounds__(512, 8) void kC(const float* __restrict__ X,
                                             const float* __restrict__ wr,
                                             const float* __restrict__ wi,
                                             float* __restrict__ y) {
    __shared__ float Xs[CIN_ * 32];        // 8 KB
    __shared__ float Pred[8][16][2];
    __shared__ float Csh[32];
    const int row = blockIdx.x;            // b*COUT_ + o
    const int b = row >> 6, o = row & 63;
    const int tid = threadIdx.x;

    // stage X[b,:,:] (one float4 per thread)
    ((float4*)Xs)[tid] = ((const float4*)(X + (size_t)b * CIN_ * 32))[tid];
    __syncthreads();

    // contraction over Cin: thread (k, p) handles i = 2p, 2p+1
    {
        const int k = tid & 15, p = tid >> 4;
        float pr = 0.f, pi = 0.f;
#pragma unroll
        for (int mI = 0; mI < 2; ++mI) {
            const int i = 2 * p + mI;
            const float xre = Xs[i * 32 + 2 * k];
            const float xim = Xs[i * 32 + 2 * k + 1];
            const float wrv = wr[(i * COUT_ + o) * MODES_ + k];
            const float wiv = wi[(i * COUT_ + o) * MODES_ + k];
            pr = fmaf(xre, wrv, fmaf(-xim, wiv, pr));
            pi = fmaf(xre, wiv, fmaf( xim, wrv, pi));
        }
        pr += __shfl_xor(pr, 16, 64);  pi += __shfl_xor(pi, 16, 64);
        pr += __shfl_xor(pr, 32, 64);  pi += __shfl_xor(pi, 32, 64);
        if ((tid & 63) < 16) *(float2*)&Pred[tid >> 6][k][0] = make_float2(pr, pi);
    }
    __syncthreads();
    if (tid < 32) {
        const int kk = tid >> 1, comp = tid & 1;
        float s = 0.f;
#pragma unroll
        for (int w = 0; w < 8; ++w) s += Pred[w][kk][comp];
        const float g = (kk == 0) ? (1.0f / RES_) : (2.0f / RES_);
        Csh[tid] = g * s;
    }
    __syncthreads();

    // broadcast C into SGPRs (frees 32 VGPRs vs keeping C vector-resident)
    float cr[16], ci[16];
#pragma unroll
    for (int kk = 0; kk < 16; ++kk) {
        cr[kk] = __int_as_float(__builtin_amdgcn_readfirstlane(__float_as_int(Csh[2 * kk])));
        ci[kk] = __int_as_float(__builtin_amdgcn_readfirstlane(__float_as_int(Csh[2 * kk + 1])));
    }

    // synthesis at a = tid: accumulate Er/Oi over k with rotation w <- w*u
    float su, cu;
    __sincosf((float)tid * W8192, &su, &cu);   // u = e^{2pi i a/8192}
    float wre = cu, wim = su;                  // w = u^k at k=1
    float Er0 = cr[0];                         // k=0: w=1, Re only
    float Er[8], Oi[8], Er8;
#pragma unroll
    for (int k = 1; k <= 7; ++k) {
        Er[k] = fmaf(cr[k], wre, -ci[k] * wim);
        Oi[k] = fmaf(cr[k], wim,  ci[k] * wre);
        const float nre = fmaf(wre, cu, -wim * su);
        wim = fmaf(wre, su, wim * cu);
        wre = nre;
    }
    Er8 = fmaf(cr[8], wre, -ci[8] * wim);      // e^{i pi bb} real: Im dropped
    {
        const float nre = fmaf(wre, cu, -wim * su);
        wim = fmaf(wre, su, wim * cu);
        wre = nre;
    }
#pragma unroll
    for (int k = 9; k <= 15; ++k) {
        const int q = 16 - k;
        Er[q] = fmaf( cr[k], wre, Er[q]);
        Er[q] = fmaf(-ci[k], wim, Er[q]);
        Oi[q] = fmaf(-cr[k], wim, Oi[q]);
        Oi[q] = fmaf(-ci[k], wre, Oi[q]);
        if (k < 15) {
            const float nre = fmaf(wre, cu, -wim * su);
            wim = fmaf(wre, su, wim * cu);
            wre = nre;
        }
    }

    // 16-pt synthesis over bb; store each result immediately (no yv array)
    float* __restrict__ yr = y + (size_t)row * RES_ + tid;
    {
        float Cc = Er0 + Er8;
#pragma unroll
        for (int q = 1; q <= 7; ++q) Cc += Er[q];
        yr[0] = Cc;
    }
    {
        float Cc = Er0 + Er8;                  // bb=8: cos = (-1)^q, sin = 0
#pragma unroll
        for (int q = 1; q <= 7; ++q) Cc += (q & 1) ? -Er[q] : Er[q];
        yr[NA * 8] = Cc;
    }
#pragma unroll
    for (int bb = 1; bb <= 7; ++bb) {
        float Cc = (bb & 1) ? (Er0 - Er8) : (Er0 + Er8);
        float Ss = 0.f;
#pragma unroll
        for (int q = 1; q <= 7; ++q) {
            Cc = fmaf(Er[q], COS16[(q * bb) & 15], Cc);
            Ss = fmaf(Oi[q], SIN16[(q * bb) & 15], Ss);
        }
        yr[NA * bb]        = Cc - Ss;
        yr[NA * (16 - bb)] = Cc + Ss;
    }
}

extern "C" void kernel_launch(void* const* d_in, const int* in_sizes, int n_in,
                              void* d_out, int out_size, void* d_ws, size_t ws_size,
                              hipStream_t stream) {
    const float* x  = (const float*)d_in[0];
    const float* wr = (const float*)d_in[1];
    const float* wi = (const float*)d_in[2];
    float* out = (float*)d_out;
    float* X = (float*)d_ws;               // [4096][32] = 512 KB

    kA<<<dim3(B_ * CIN_), dim3(512), 0, stream>>>(x, X);
    kC<<<dim3(B_ * COUT_), dim3(512), 0, stream>>>(X, wr, wi, out);
}

// Round 3
// 231.677 us; speedup vs baseline: 1.0278x; 1.0213x over previous
//
#include <hip/hip_runtime.h>
#include <math.h>

// SpectralConv1d: y = irfft( einsum('bim,iom->bom', rfft(x)[:,:,:16], W) )
// B=64, Cin=64, Cout=64, MODES=16, RES=8192.
// v3.1: all HBM streaming at 16 B/lane. kA stages x-row to LDS via float4 then
// reads strided from LDS (union with Ts). kC synthesizes into an LDS y-row
// buffer (union with Xs) and streams out with nontemporal 16B stores.
// (v3 compile fix: nontemporal builtin needs a native ext_vector_type.)

#define B_     64
#define CIN_   64
#define COUT_  64
#define MODES_ 16
#define RES_   8192
#define NA     512          // RES_/16
#define TPITCH 515          // float2 pitch for Ts rows; 515 % 16 == 3 (bank spread)
#define W8192  7.66990393942820428e-4f   // 2*pi/8192

typedef float f32x4 __attribute__((ext_vector_type(4)));

__device__ static constexpr float COS16[16] = {
     1.0f,  0.92387953251128674f,  0.70710678118654752f,  0.38268343236508977f,
     0.0f, -0.38268343236508977f, -0.70710678118654752f, -0.92387953251128674f,
    -1.0f, -0.92387953251128674f, -0.70710678118654752f, -0.38268343236508977f,
     0.0f,  0.38268343236508977f,  0.70710678118654752f,  0.92387953251128674f
};
__device__ static constexpr float SIN16[16] = {
     0.0f,  0.38268343236508977f,  0.70710678118654752f,  0.92387953251128674f,
     1.0f,  0.92387953251128674f,  0.70710678118654752f,  0.38268343236508977f,
     0.0f, -0.38268343236508977f, -0.70710678118654752f, -0.92387953251128674f,
    -1.0f, -0.92387953251128674f, -0.70710678118654752f, -0.38268343236508977f
};

// ---------------- Stage A: X[row,k] = sum_n x[row,n] e^{-2pi i k n/8192}, k=0..15
// One block per row (4096 blocks), 512 threads.
__global__ __launch_bounds__(512, 8) void kA(const float* __restrict__ x,
                                             float* __restrict__ X) {
    // Union buffer: phase 0 = x-row staging (8192 floats); phase 1+ = Ts
    // (9 rows of TPITCH float2 = 9270 floats). 37080 B.
    __shared__ __align__(16) float S[9 * TPITCH * 2];
    __shared__ float Pred[8][16][2];       // per-wave partials: 1024 B
    const int row = blockIdx.x;
    const int tid = threadIdx.x;
    const float* __restrict__ xr = x + (size_t)row * RES_;

    // Phase 0: stage x row (32 KB) into LDS, fully coalesced float4.
    const f32x4* __restrict__ xv = (const f32x4*)xr;
#pragma unroll
    for (int j = 0; j < 4; ++j) {
        const f32x4 v = xv[tid + 512 * j];
        ((f32x4*)S)[tid + 512 * j] = v;
    }
    __syncthreads();

    // Phase 1: 16-pt real DFT over b at a = tid (reads from LDS, lane-stride 4B).
    float m[16];
#pragma unroll
    for (int b = 0; b < 16; ++b) m[b] = S[tid + NA * b];
    float ev[8], ov[8];
#pragma unroll
    for (int b = 1; b <= 7; ++b) { ev[b] = m[b] + m[16 - b]; ov[b] = m[b] - m[16 - b]; }
    const float x0 = m[0], x8 = m[8];
    __syncthreads();                       // all x reads done; S becomes Ts

    float2* __restrict__ Ts = (float2*)S;
#pragma unroll
    for (int k = 0; k <= 8; ++k) {
        float sr = (k & 1) ? (x0 - x8) : (x0 + x8);
        float si = 0.f;
#pragma unroll
        for (int b = 1; b <= 7; ++b) {
            sr = fmaf(ev[b],  COS16[(k * b) & 15], sr);
            si = fmaf(ov[b], -SIN16[(k * b) & 15], si);
        }
        Ts[k * TPITCH + tid] = make_float2(sr, si);
    }
    __syncthreads();

    // Phase 2: X[k] = sum_a e^{-2pi i k a/8192} t_k[a]; a = c + 32*j.
    // Hermitian t: k>8 -> conj t[16-k]; sign folded into the twiddle.
    const int k  = tid & 15;
    const int c  = tid >> 4;               // 0..31
    const int kp = (k <= 8) ? k : 16 - k;
    const float sgn = (k <= 8) ? 1.f : -1.f;
    float sA, cA, sB, cB;
    __sincosf((float)(k * c)  * W8192, &sA, &cA);
    __sincosf((float)(k * 32) * W8192, &sB, &cB);
    float wre = cA, wim = -sgn * sA;       // primed: wim' = sgn*wim_true
    const float sre = cB, sim = -sgn * sB; // primed step
    float accr = 0.f, acci = 0.f;          // acci holds sgn*Im
    const float2* __restrict__ Tp = &Ts[kp * TPITCH + c];
#pragma unroll
    for (int j = 0; j < 16; ++j) {
        const float2 t = Tp[32 * j];
        accr = fmaf(wre, t.x, fmaf(-wim, t.y, accr));
        acci = fmaf(wre, t.y, fmaf( wim, t.x, acci));
        const float nre = fmaf(wre, sre, -wim * sim);
        wim = fmaf(wre, sim, wim * sre);
        wre = nre;
    }
    acci *= sgn;
    // reduce the 4 c-values that share k within this wave
    accr += __shfl_xor(accr, 16, 64);  acci += __shfl_xor(acci, 16, 64);
    accr += __shfl_xor(accr, 32, 64);  acci += __shfl_xor(acci, 32, 64);
    if ((tid & 63) < 16) {
        *(float2*)&Pred[tid >> 6][k][0] = make_float2(accr, acci);
    }
    __syncthreads();
    if (tid < 32) {                        // tid = 2k+comp
        const int kk = tid >> 1, comp = tid & 1;
        float s = 0.f;
#pragma unroll
        for (int w = 0; w < 8; ++w) s += Pred[w][kk][comp];
        X[row * 32 + tid] = s;
    }
}

// ---------------- Stage C (fused B+C): per block (b,o):
//   C_k = g_k * sum_i X[b,i,k] * W[i,o,k]   (g_0=1/N, g_k=2/N)
//   y[a+512*bb] = sum_k Re( C_k e^{2pi i k a/8192} e^{i pi k bb/8} )
// One block per output row (4096 blocks), 512 threads, one a per thread.
__global__ __launch_bounds__(512, 8) void kC(const float* __restrict__ X,
                                             const float* __restrict__ wr,
                                             const float* __restrict__ wi,
                                             float* __restrict__ y) {
    // Union buffer: phase 0-1 = Xs (2048 floats); synthesis = y-row (8192 floats).
    __shared__ __align__(16) float S[RES_];   // 32 KB
    __shared__ float Pred[8][16][2];
    __shared__ float Csh[32];
    const int row = blockIdx.x;            // b*COUT_ + o
    const int b = row >> 6, o = row & 63;
    const int tid = threadIdx.x;

    // stage X[b,:,:] (one float4 per thread, 2048 floats)
    ((f32x4*)S)[tid] = ((const f32x4*)(X + (size_t)b * CIN_ * 32))[tid];
    __syncthreads();

    // contraction over Cin: thread (k, p) handles i = 2p, 2p+1
    {
        const int k = tid & 15, p = tid >> 4;
        float pr = 0.f, pi = 0.f;
#pragma unroll
        for (int mI = 0; mI < 2; ++mI) {
            const int i = 2 * p + mI;
            const float2 xv = *(const float2*)&S[i * 32 + 2 * k];
            const float wrv = wr[(i * COUT_ + o) * MODES_ + k];
            const float wiv = wi[(i * COUT_ + o) * MODES_ + k];
            pr = fmaf(xv.x, wrv, fmaf(-xv.y, wiv, pr));
            pi = fmaf(xv.x, wiv, fmaf( xv.y, wrv, pi));
        }
        pr += __shfl_xor(pr, 16, 64);  pi += __shfl_xor(pi, 16, 64);
        pr += __shfl_xor(pr, 32, 64);  pi += __shfl_xor(pi, 32, 64);
        if ((tid & 63) < 16) *(float2*)&Pred[tid >> 6][k][0] = make_float2(pr, pi);
    }
    __syncthreads();
    if (tid < 32) {
        const int kk = tid >> 1, comp = tid & 1;
        float s = 0.f;
#pragma unroll
        for (int w = 0; w < 8; ++w) s += Pred[w][kk][comp];
        const float g = (kk == 0) ? (1.0f / RES_) : (2.0f / RES_);
        Csh[tid] = g * s;
    }
    __syncthreads();

    // broadcast C into SGPRs
    float cr[16], ci[16];
#pragma unroll
    for (int kk = 0; kk < 16; ++kk) {
        cr[kk] = __int_as_float(__builtin_amdgcn_readfirstlane(__float_as_int(Csh[2 * kk])));
        ci[kk] = __int_as_float(__builtin_amdgcn_readfirstlane(__float_as_int(Csh[2 * kk + 1])));
    }

    // synthesis at a = tid: accumulate Er/Oi over k with rotation w <- w*u
    float su, cu;
    __sincosf((float)tid * W8192, &su, &cu);   // u = e^{2pi i a/8192}
    float wre = cu, wim = su;                  // w = u^k at k=1
    float Er0 = cr[0];                         // k=0: w=1, Re only
    float Er[8], Oi[8], Er8;
#pragma unroll
    for (int k = 1; k <= 7; ++k) {
        Er[k] = fmaf(cr[k], wre, -ci[k] * wim);
        Oi[k] = fmaf(cr[k], wim,  ci[k] * wre);
        const float nre = fmaf(wre, cu, -wim * su);
        wim = fmaf(wre, su, wim * cu);
        wre = nre;
    }
    Er8 = fmaf(cr[8], wre, -ci[8] * wim);      // e^{i pi bb} real: Im dropped
    {
        const float nre = fmaf(wre, cu, -wim * su);
        wim = fmaf(wre, su, wim * cu);
        wre = nre;
    }
#pragma unroll
    for (int k = 9; k <= 15; ++k) {
        const int q = 16 - k;
        Er[q] = fmaf( cr[k], wre, Er[q]);
        Er[q] = fmaf(-ci[k], wim, Er[q]);
        Oi[q] = fmaf(-cr[k], wim, Oi[q]);
        Oi[q] = fmaf(-ci[k], wre, Oi[q]);
        if (k < 15) {
            const float nre = fmaf(wre, cu, -wim * su);
            wim = fmaf(wre, su, wim * cu);
            wre = nre;
        }
    }

    // 16-pt synthesis over bb; write to LDS y-row buffer (S reused; safe: all
    // Xs reads completed before the sync after the contraction).
    {
        float Cc = Er0 + Er8;                  // bb=0
#pragma unroll
        for (int q = 1; q <= 7; ++q) Cc += Er[q];
        S[tid] = Cc;
    }
    {
        float Cc = Er0 + Er8;                  // bb=8: cos = (-1)^q, sin = 0
#pragma unroll
        for (int q = 1; q <= 7; ++q) Cc += (q & 1) ? -Er[q] : Er[q];
        S[NA * 8 + tid] = Cc;
    }
#pragma unroll
    for (int bb = 1; bb <= 7; ++bb) {
        float Cc = (bb & 1) ? (Er0 - Er8) : (Er0 + Er8);
        float Ss = 0.f;
#pragma unroll
        for (int q = 1; q <= 7; ++q) {
            Cc = fmaf(Er[q], COS16[(q * bb) & 15], Cc);
            Ss = fmaf(Oi[q], SIN16[(q * bb) & 15], Ss);
        }
        S[NA * bb + tid]        = Cc - Ss;
        S[NA * (16 - bb) + tid] = Cc + Ss;
    }
    __syncthreads();

    // stream the y row out: 4x nontemporal 16B stores per thread, coalesced.
    f32x4* __restrict__ yv4 = (f32x4*)(y + (size_t)row * RES_);
#pragma unroll
    for (int j = 0; j < 4; ++j)
        __builtin_nontemporal_store(((const f32x4*)S)[tid + 512 * j],
                                    yv4 + tid + 512 * j);
}

extern "C" void kernel_launch(void* const* d_in, const int* in_sizes, int n_in,
                              void* d_out, int out_size, void* d_ws, size_t ws_size,
                              hipStream_t stream) {
    const float* x  = (const float*)d_in[0];
    const float* wr = (const float*)d_in[1];
    const float* wi = (const float*)d_in[2];
    float* out = (float*)d_out;
    float* X = (float*)d_ws;               // [4096][32] = 512 KB

    kA<<<dim3(B_ * CIN_), dim3(512), 0, stream>>>(x, X);
    kC<<<dim3(B_ * COUT_), dim3(512), 0, stream>>>(X, wr, wi, out);
}